// Round 7
// baseline (303.454 us; speedup 1.0000x reference)
//
#include <hip/hip_runtime.h>

#define N_NODES   100000
#define N_EDGES   1600000
#define IN_DIM    128
#define HID_DIM   64
#define N_CLASSES 40
#define NCPAD     48       // classes padded to 3 MFMA tiles

#define NBUCK 782          // ceil(100000 / 128) coarse buckets, bucket = row >> 7
#define BCAP  2816         // bucket capacity incl. pad-to-8 (mean ~2494, ~6 sigma)
#define EPB   1600         // edges per block in pass A; 1000 blocks -> 4 blocks/CU

typedef __attribute__((ext_vector_type(8))) short bf16x8;
typedef __attribute__((ext_vector_type(4))) float f32x4;

__device__ inline short f2bf(float f) {
    unsigned u = __float_as_uint(f);
    unsigned r = (u + 0x7FFFu + ((u >> 16) & 1u)) >> 16;   // round-to-nearest-even
    return (short)r;
}
__device__ inline float bf2f(unsigned short s) {
    return __uint_as_float(((unsigned)s) << 16);
}
__device__ inline float bflo(unsigned w) { return __uint_as_float(w << 16); }
__device__ inline float bfhi(unsigned w) { return __uint_as_float(w & 0xFFFF0000u); }

// ---------------- weight prep ----------------
__global__ __launch_bounds__(256) void prep_weights(const float* __restrict__ W1,
                                                    const float* __restrict__ W2,
                                                    const float* __restrict__ Wc,
                                                    short* __restrict__ W1t,
                                                    short* __restrict__ W2t,
                                                    short* __restrict__ Wct) {
    for (int i = blockIdx.x * 256 + threadIdx.x; i < IN_DIM * HID_DIM; i += gridDim.x * 256) {
        int n = i >> 7, k = i & 127;
        W1t[i] = f2bf(W1[k * HID_DIM + n]);
    }
    for (int i = blockIdx.x * 256 + threadIdx.x; i < HID_DIM * HID_DIM; i += gridDim.x * 256) {
        int n = i >> 6, k = i & 63;
        W2t[i] = f2bf(W2[k * HID_DIM + n]);
    }
    for (int i = blockIdx.x * 256 + threadIdx.x; i < NCPAD * HID_DIM; i += gridDim.x * 256) {
        int c = i >> 6, k = i & 63;
        Wct[i] = (c < N_CLASSES) ? f2bf(Wc[k * N_CLASSES + c]) : 0;
    }
}

// ---------------- GEMM1 (MFMA): hbf[n,64] = bf16(x[n,128] @ W1 + b1) ----------------
__global__ __launch_bounds__(256) void gemm1_mfma(const float* __restrict__ x,
                                                  const short* __restrict__ W1t,
                                                  const float* __restrict__ b1,
                                                  unsigned short* __restrict__ out) {
    int wave = threadIdx.x >> 6;
    int lane = threadIdx.x & 63;
    int node0 = blockIdx.x * 64 + wave * 16;
    if (node0 >= N_NODES) return;
    int m = lane & 15;
    int q = lane >> 4;
    const float* xrow = x + (size_t)(node0 + m) * IN_DIM;
    f32x4 acc0 = {0,0,0,0}, acc1 = {0,0,0,0}, acc2 = {0,0,0,0}, acc3 = {0,0,0,0};
#pragma unroll
    for (int kb = 0; kb < 4; ++kb) {
        int k0 = kb * 32 + q * 8;
        float4 a0 = *(const float4*)(xrow + k0);
        float4 a1 = *(const float4*)(xrow + k0 + 4);
        bf16x8 af;
        af[0]=f2bf(a0.x); af[1]=f2bf(a0.y); af[2]=f2bf(a0.z); af[3]=f2bf(a0.w);
        af[4]=f2bf(a1.x); af[5]=f2bf(a1.y); af[6]=f2bf(a1.z); af[7]=f2bf(a1.w);
        bf16x8 bf0 = *(const bf16x8*)(W1t + ( 0 + m) * IN_DIM + k0);
        bf16x8 bf1 = *(const bf16x8*)(W1t + (16 + m) * IN_DIM + k0);
        bf16x8 bf2 = *(const bf16x8*)(W1t + (32 + m) * IN_DIM + k0);
        bf16x8 bf3 = *(const bf16x8*)(W1t + (48 + m) * IN_DIM + k0);
        acc0 = __builtin_amdgcn_mfma_f32_16x16x32_bf16(af, bf0, acc0, 0, 0, 0);
        acc1 = __builtin_amdgcn_mfma_f32_16x16x32_bf16(af, bf1, acc1, 0, 0, 0);
        acc2 = __builtin_amdgcn_mfma_f32_16x16x32_bf16(af, bf2, acc2, 0, 0, 0);
        acc3 = __builtin_amdgcn_mfma_f32_16x16x32_bf16(af, bf3, acc3, 0, 0, 0);
    }
    f32x4 accs[4] = {acc0, acc1, acc2, acc3};
#pragma unroll
    for (int t = 0; t < 4; ++t) {
        float bias = b1[t * 16 + m];
#pragma unroll
        for (int r = 0; r < 4; ++r) {
            int node = node0 + q * 4 + r;            // C/D: col=lane&15, row=q*4+r
            out[(size_t)node * HID_DIM + t * 16 + m] = (unsigned short)f2bf(accs[t][r] + bias);
        }
    }
}

// ---------------- GEMM2 (MFMA): hbf_out[n,64] = bf16(relu(hbf[n,64]) @ W2 + b2) ----------------
__global__ __launch_bounds__(256) void gemm2_mfma(const unsigned short* __restrict__ h,
                                                  const short* __restrict__ W2t,
                                                  const float* __restrict__ b2,
                                                  unsigned short* __restrict__ out) {
    int wave = threadIdx.x >> 6;
    int lane = threadIdx.x & 63;
    int node0 = blockIdx.x * 64 + wave * 16;
    if (node0 >= N_NODES) return;
    int m = lane & 15;
    int q = lane >> 4;
    const unsigned short* hrow = h + (size_t)(node0 + m) * HID_DIM;
    f32x4 acc0 = {0,0,0,0}, acc1 = {0,0,0,0}, acc2 = {0,0,0,0}, acc3 = {0,0,0,0};
#pragma unroll
    for (int kb = 0; kb < 2; ++kb) {
        int k0 = kb * 32 + q * 8;
        bf16x8 af = *(const bf16x8*)(hrow + k0);
#pragma unroll
        for (int j = 0; j < 8; ++j)
            af[j] = ((unsigned short)af[j] & 0x8000u) ? 0 : af[j];   // bf16 ReLU
        bf16x8 bf0 = *(const bf16x8*)(W2t + ( 0 + m) * HID_DIM + k0);
        bf16x8 bf1 = *(const bf16x8*)(W2t + (16 + m) * HID_DIM + k0);
        bf16x8 bf2 = *(const bf16x8*)(W2t + (32 + m) * HID_DIM + k0);
        bf16x8 bf3 = *(const bf16x8*)(W2t + (48 + m) * HID_DIM + k0);
        acc0 = __builtin_amdgcn_mfma_f32_16x16x32_bf16(af, bf0, acc0, 0, 0, 0);
        acc1 = __builtin_amdgcn_mfma_f32_16x16x32_bf16(af, bf1, acc1, 0, 0, 0);
        acc2 = __builtin_amdgcn_mfma_f32_16x16x32_bf16(af, bf2, acc2, 0, 0, 0);
        acc3 = __builtin_amdgcn_mfma_f32_16x16x32_bf16(af, bf3, acc3, 0, 0, 0);
    }
    f32x4 accs[4] = {acc0, acc1, acc2, acc3};
#pragma unroll
    for (int t = 0; t < 4; ++t) {
        float bias = b2[t * 16 + m];
#pragma unroll
        for (int r = 0; r < 4; ++r) {
            int node = node0 + q * 4 + r;
            out[(size_t)node * HID_DIM + t * 16 + m] = (unsigned short)f2bf(accs[t][r] + bias);
        }
    }
}

// ---------------- Pass A: partition edges into 782 coarse buckets (row >> 7) ----------------
__global__ __launch_bounds__(256) void part_a(const int* __restrict__ erow,
                                              const int* __restrict__ ecol,
                                              const float* __restrict__ eval,
                                              int* __restrict__ bcnt,
                                              int2* __restrict__ tmp) {
    __shared__ int srow[EPB];        // 6.4 KB
    __shared__ int hist[NBUCK];
    __shared__ int gbase[NBUCK];
    __shared__ int cur[NBUCK];
    int e0 = blockIdx.x * EPB;
    for (int i = threadIdx.x; i < NBUCK; i += 256) { hist[i] = 0; cur[i] = 0; }
    __syncthreads();
    for (int i = threadIdx.x; i < EPB; i += 256) {
        int e = e0 + i;
        int r = (e < N_EDGES) ? erow[e] : -1;
        srow[i] = r;
        if (r >= 0) atomicAdd(&hist[r >> 7], 1);
    }
    __syncthreads();
    for (int i = threadIdx.x; i < NBUCK; i += 256) {
        int n = hist[i];
        gbase[i] = n ? atomicAdd(&bcnt[i], n) : 0;
    }
    __syncthreads();
    for (int i = threadIdx.x; i < EPB; i += 256) {
        int r = srow[i];
        if (r < 0) continue;
        int e = e0 + i;
        int b = r >> 7;
        int slot = gbase[b] + atomicAdd(&cur[b], 1);
        if (slot < BCAP)
            tmp[(size_t)b * BCAP + slot] =
                make_int2(((r & 127) << 17) | ecol[e], __float_as_int(eval[e]));
    }
}

// ---------------- Pass B: sort bucket by local row, pad each row to mult-of-8, col *= 64 ----------------
__global__ __launch_bounds__(256) void part_b(const int* __restrict__ bcnt,
                                              int2* __restrict__ tmp,
                                              int2* __restrict__ rowmeta) {
    __shared__ int2 ein[BCAP];       // 22.5 KB
    __shared__ int2 eout[BCAP];      // 22.5 KB
    __shared__ int hist[128], pad[128], basep[128], cur[128], scan[128];
    int b = blockIdx.x;
    int nb = bcnt[b]; if (nb > BCAP) nb = BCAP;
    for (int i = threadIdx.x; i < nb; i += 256) ein[i] = tmp[(size_t)b * BCAP + i];
    if (threadIdx.x < 128) { hist[threadIdx.x] = 0; cur[threadIdx.x] = 0; }
    __syncthreads();
    for (int i = threadIdx.x; i < nb; i += 256)
        atomicAdd(&hist[(ein[i].x >> 17) & 127], 1);
    __syncthreads();
    if (threadIdx.x < 128) {
        pad[threadIdx.x] = (hist[threadIdx.x] + 7) & ~7;   // pad to multiple of 8
        scan[threadIdx.x] = pad[threadIdx.x];
    }
    __syncthreads();
    for (int off = 1; off < 128; off <<= 1) {
        int t = 0;
        if (threadIdx.x < 128 && threadIdx.x >= off) t = scan[threadIdx.x - off];
        __syncthreads();
        if (threadIdx.x < 128) scan[threadIdx.x] += t;
        __syncthreads();
    }
    if (threadIdx.x < 128) basep[threadIdx.x] = scan[threadIdx.x] - pad[threadIdx.x];
    __syncthreads();
    int ntot = scan[127]; if (ntot > BCAP) ntot = BCAP;
    for (int i = threadIdx.x; i < nb; i += 256) {
        int lr = (ein[i].x >> 17) & 127;
        int p = basep[lr] + atomicAdd(&cur[lr], 1);
        if (p < BCAP) eout[p] = make_int2((ein[i].x & 0x1FFFF) << 6, ein[i].y);
    }
    __syncthreads();
    if (threadIdx.x < 128) {
        int pe = basep[threadIdx.x] + pad[threadIdx.x];
        for (int p = basep[threadIdx.x] + hist[threadIdx.x]; p < pe && p < BCAP; ++p)
            eout[p] = make_int2(0, 0);
    }
    __syncthreads();
    for (int i = threadIdx.x; i < ntot; i += 256) tmp[(size_t)b * BCAP + i] = eout[i];
    if (threadIdx.x < 128) {
        int r = b * 128 + threadIdx.x;
        if (r < N_NODES)
            rowmeta[r] = make_int2(b * BCAP + basep[threadIdx.x], pad[threadIdx.x]);
    }
}

// ---------------- SpMM v3: one wave per row; all gathers issued upfront (max MLP) ----------------
// lane = (g = lane>>3: edge subgroup, dq = lane&7: dim octet). 16 B/lane dwordx4 gathers.
__global__ __launch_bounds__(256) void spmm_csr(const int2* __restrict__ rowmeta,
                                                const int2* __restrict__ ecv,
                                                const unsigned short* __restrict__ dense,
                                                unsigned short* __restrict__ out) {
    int r = blockIdx.x * 4 + (threadIdx.x >> 6);
    if (r >= N_NODES) return;
    int lane = threadIdx.x & 63;
    int g  = lane >> 3;
    int dq = lane & 7;
    int2 meta = rowmeta[r];
    int rs   = __builtin_amdgcn_readfirstlane(meta.x);
    int degp = __builtin_amdgcn_readfirstlane(meta.y);   // padded degree (multiple of 8)
    float a0=0,a1=0,a2=0,a3=0,a4=0,a5=0,a6=0,a7=0;
    if (degp > 0) {
        // preload this row's edge metadata: lane i -> edge rs+i (coalesced 512 B)
        int2 em = ecv[rs + (lane < degp ? lane : degp - 1)];
        int iters = degp >> 3; if (iters > 8) iters = 8;
        uint4 d[8];
        // issue all gathers back-to-back: up to 8 outstanding loads per wave
#pragma unroll
        for (int t = 0; t < 8; ++t) {
            if (t < iters) {
                int col = __shfl(em.x, t * 8 + g);
                d[t] = *(const uint4*)(dense + (size_t)col + (dq << 3));
            }
        }
#pragma unroll
        for (int t = 0; t < 8; ++t) {
            if (t < iters) {
                float v = __shfl(__int_as_float(em.y), t * 8 + g);
                a0 = fmaf(v, bflo(d[t].x), a0);  a1 = fmaf(v, bfhi(d[t].x), a1);
                a2 = fmaf(v, bflo(d[t].y), a2);  a3 = fmaf(v, bfhi(d[t].y), a3);
                a4 = fmaf(v, bflo(d[t].z), a4);  a5 = fmaf(v, bfhi(d[t].z), a5);
                a6 = fmaf(v, bflo(d[t].w), a6);  a7 = fmaf(v, bfhi(d[t].w), a7);
            }
        }
        // tail for degp > 64 (essentially never with Poisson(16) rows)
        for (int e = rs + 64; e < rs + degp; ++e) {
            int2 ee = ecv[e];
            if (g == 0) {
                float tv = __int_as_float(ee.y);
                uint4 td = *(const uint4*)(dense + (size_t)ee.x + (dq << 3));
                a0 = fmaf(tv, bflo(td.x), a0);  a1 = fmaf(tv, bfhi(td.x), a1);
                a2 = fmaf(tv, bflo(td.y), a2);  a3 = fmaf(tv, bfhi(td.y), a3);
                a4 = fmaf(tv, bflo(td.z), a4);  a5 = fmaf(tv, bfhi(td.z), a5);
                a6 = fmaf(tv, bflo(td.w), a6);  a7 = fmaf(tv, bfhi(td.w), a7);
            }
        }
    }
    // butterfly-reduce the 8 edge-subgroups (xor 8, 16, 32)
#pragma unroll
    for (int off = 8; off < 64; off <<= 1) {
        a0 += __shfl_xor(a0, off); a1 += __shfl_xor(a1, off);
        a2 += __shfl_xor(a2, off); a3 += __shfl_xor(a3, off);
        a4 += __shfl_xor(a4, off); a5 += __shfl_xor(a5, off);
        a6 += __shfl_xor(a6, off); a7 += __shfl_xor(a7, off);
    }
    if (lane < 8) {
        uint4 o;
        o.x = (unsigned short)f2bf(a0) | ((unsigned)(unsigned short)f2bf(a1) << 16);
        o.y = (unsigned short)f2bf(a2) | ((unsigned)(unsigned short)f2bf(a3) << 16);
        o.z = (unsigned short)f2bf(a4) | ((unsigned)(unsigned short)f2bf(a5) << 16);
        o.w = (unsigned short)f2bf(a6) | ((unsigned)(unsigned short)f2bf(a7) << 16);
        *(uint4*)(out + (size_t)r * HID_DIM + lane * 8) = o;
    }
}

// ---------------- Classifier (MFMA): out = log_softmax(h @ Wc + bc) ----------------
#define SLOGW 49
__global__ __launch_bounds__(256) void classify_mfma(const unsigned short* __restrict__ h,
                                                     const short* __restrict__ Wct,
                                                     const float* __restrict__ bc,
                                                     float* __restrict__ out) {
    __shared__ float slog[64 * SLOGW];
    __shared__ float smax[64], slse[64];
    int wave = threadIdx.x >> 6;
    int lane = threadIdx.x & 63;
    int node0 = blockIdx.x * 64;
    int wnode0 = node0 + wave * 16;
    int m = lane & 15;
    int q = lane >> 4;
    int arow = wnode0 + m; if (arow >= N_NODES) arow = N_NODES - 1;
    const unsigned short* hrow = h + (size_t)arow * HID_DIM;
    f32x4 acc0 = {0,0,0,0}, acc1 = {0,0,0,0}, acc2 = {0,0,0,0};
#pragma unroll
    for (int kb = 0; kb < 2; ++kb) {
        int k0 = kb * 32 + q * 8;
        bf16x8 af = *(const bf16x8*)(hrow + k0);
        bf16x8 bf0 = *(const bf16x8*)(Wct + ( 0 + m) * HID_DIM + k0);
        bf16x8 bf1 = *(const bf16x8*)(Wct + (16 + m) * HID_DIM + k0);
        bf16x8 bf2 = *(const bf16x8*)(Wct + (32 + m) * HID_DIM + k0);
        acc0 = __builtin_amdgcn_mfma_f32_16x16x32_bf16(af, bf0, acc0, 0, 0, 0);
        acc1 = __builtin_amdgcn_mfma_f32_16x16x32_bf16(af, bf1, acc1, 0, 0, 0);
        acc2 = __builtin_amdgcn_mfma_f32_16x16x32_bf16(af, bf2, acc2, 0, 0, 0);
    }
    f32x4 accs[3] = {acc0, acc1, acc2};
#pragma unroll
    for (int t = 0; t < 3; ++t) {
        int cls = t * 16 + m;
        float bias = (cls < N_CLASSES) ? bc[cls] : 0.f;
#pragma unroll
        for (int r = 0; r < 4; ++r) {
            int nl = wave * 16 + q * 4 + r;
            slog[nl * SLOGW + cls] = accs[t][r] + bias;
        }
    }
    __syncthreads();
    if (threadIdx.x < 64) {
        int nl = threadIdx.x;
        float mx = -1e30f;
        for (int c = 0; c < N_CLASSES; ++c) mx = fmaxf(mx, slog[nl * SLOGW + c]);
        float s = 0.f;
        for (int c = 0; c < N_CLASSES; ++c) s += expf(slog[nl * SLOGW + c] - mx);
        smax[nl] = mx;
        slse[nl] = logf(s);
    }
    __syncthreads();
    for (int i = threadIdx.x; i < 64 * N_CLASSES; i += 256) {
        long long gi = (long long)node0 * N_CLASSES + i;
        if (gi < (long long)N_NODES * N_CLASSES) {
            int nl = i / N_CLASSES, c = i - nl * N_CLASSES;
            out[gi] = slog[nl * SLOGW + c] - smax[nl] - slse[nl];
        }
    }
}

extern "C" void kernel_launch(void* const* d_in, const int* in_sizes, int n_in,
                              void* d_out, int out_size, void* d_ws, size_t ws_size,
                              hipStream_t stream) {
    const float* x    = (const float*)d_in[0];
    const int*   erow = (const int*)  d_in[1];
    const int*   ecol = (const int*)  d_in[2];
    const float* eval = (const float*)d_in[3];
    const float* W1   = (const float*)d_in[4];
    const float* b1   = (const float*)d_in[5];
    const float* W2   = (const float*)d_in[6];
    const float* b2   = (const float*)d_in[7];
    const float* Wc   = (const float*)d_in[8];
    const float* bc   = (const float*)d_in[9];
    float* out = (float*)d_out;

    // ---- workspace layout ----
    char* ws = (char*)d_ws;
    size_t off = 0;
    auto alloc = [&](size_t bytes) { char* p = ws + off; off += (bytes + 255) & ~(size_t)255; return p; };
    unsigned short* bufA = (unsigned short*)alloc((size_t)N_NODES * HID_DIM * sizeof(short)); // 12.8 MB
    unsigned short* bufB = (unsigned short*)alloc((size_t)N_NODES * HID_DIM * sizeof(short)); // 12.8 MB
    int2*  tmp     = (int2*) alloc((size_t)NBUCK * BCAP * sizeof(int2));       // 17.6 MB
    int2*  rowmeta = (int2*) alloc((size_t)N_NODES * sizeof(int2));            // 0.8 MB
    int*   bcnt    = (int*)  alloc(NBUCK * sizeof(int));
    short* W1t     = (short*)alloc((size_t)IN_DIM * HID_DIM * sizeof(short));
    short* W2t     = (short*)alloc((size_t)HID_DIM * HID_DIM * sizeof(short));
    short* Wct     = (short*)alloc((size_t)NCPAD * HID_DIM * sizeof(short));

    const int tile_grid = (N_NODES + 63) / 64;     // 1563
    const int spmm_grid = (N_NODES + 3) / 4;
    const int grid_a    = (N_EDGES + EPB - 1) / EPB;   // 1000

    // ---- build bucketed padded CSR (reused by both spmm layers) + weight prep ----
    hipMemsetAsync(bcnt, 0, NBUCK * sizeof(int), stream);
    prep_weights<<<32, 256, 0, stream>>>(W1, W2, Wc, W1t, W2t, Wct);
    part_a<<<grid_a, 256, 0, stream>>>(erow, ecol, eval, bcnt, tmp);
    part_b<<<NBUCK, 256, 0, stream>>>(bcnt, tmp, rowmeta);

    // ---- layer 1 ----
    gemm1_mfma<<<tile_grid, 256, 0, stream>>>(x, W1t, b1, bufA);
    spmm_csr<<<spmm_grid, 256, 0, stream>>>(rowmeta, tmp, bufA, bufB);
    // ---- layer 2 (ReLU fused into gemm2 A-load) ----
    gemm2_mfma<<<tile_grid, 256, 0, stream>>>(bufB, W2t, b2, bufA);
    spmm_csr<<<spmm_grid, 256, 0, stream>>>(rowmeta, tmp, bufA, bufB);
    // ---- classifier + log-softmax ----
    classify_mfma<<<tile_grid, 256, 0, stream>>>(bufB, Wct, bc, out);
}

// Round 8
// 279.611 us; speedup vs baseline: 1.0853x; 1.0853x over previous
//
#include <hip/hip_runtime.h>

#define N_NODES   100000
#define N_EDGES   1600000
#define IN_DIM    128
#define HID_DIM   64
#define N_CLASSES 40
#define NCPAD     48       // classes padded to 3 MFMA tiles

#define NBUCK 782          // ceil(100000 / 128) coarse buckets, bucket = row >> 7
#define BCAP  2816         // bucket capacity incl. pad-to-8 (mean ~2494, ~6 sigma)
#define EPB   6400         // edges per block in pass A; 250 * 6400 == N_EDGES exactly
#define PBLK  1024         // part_a block size: 16 waves hides scatter latency

typedef __attribute__((ext_vector_type(8))) short bf16x8;
typedef __attribute__((ext_vector_type(4))) float f32x4;

__device__ inline short f2bf(float f) {
    unsigned u = __float_as_uint(f);
    unsigned r = (u + 0x7FFFu + ((u >> 16) & 1u)) >> 16;   // round-to-nearest-even
    return (short)r;
}
__device__ inline float bf2f(unsigned short s) {
    return __uint_as_float(((unsigned)s) << 16);
}
__device__ inline float bflo(unsigned w) { return __uint_as_float(w << 16); }
__device__ inline float bfhi(unsigned w) { return __uint_as_float(w & 0xFFFF0000u); }

// ---------------- weight prep ----------------
__global__ __launch_bounds__(256) void prep_weights(const float* __restrict__ W1,
                                                    const float* __restrict__ W2,
                                                    const float* __restrict__ Wc,
                                                    short* __restrict__ W1t,
                                                    short* __restrict__ W2t,
                                                    short* __restrict__ Wct) {
    for (int i = blockIdx.x * 256 + threadIdx.x; i < IN_DIM * HID_DIM; i += gridDim.x * 256) {
        int n = i >> 7, k = i & 127;
        W1t[i] = f2bf(W1[k * HID_DIM + n]);
    }
    for (int i = blockIdx.x * 256 + threadIdx.x; i < HID_DIM * HID_DIM; i += gridDim.x * 256) {
        int n = i >> 6, k = i & 63;
        W2t[i] = f2bf(W2[k * HID_DIM + n]);
    }
    for (int i = blockIdx.x * 256 + threadIdx.x; i < NCPAD * HID_DIM; i += gridDim.x * 256) {
        int c = i >> 6, k = i & 63;
        Wct[i] = (c < N_CLASSES) ? f2bf(Wc[k * N_CLASSES + c]) : 0;
    }
}

// ---------------- GEMM1 (MFMA): hbf[n,64] = bf16(x[n,128] @ W1 + b1) ----------------
__global__ __launch_bounds__(256) void gemm1_mfma(const float* __restrict__ x,
                                                  const short* __restrict__ W1t,
                                                  const float* __restrict__ b1,
                                                  unsigned short* __restrict__ out) {
    int wave = threadIdx.x >> 6;
    int lane = threadIdx.x & 63;
    int node0 = blockIdx.x * 64 + wave * 16;
    if (node0 >= N_NODES) return;
    int m = lane & 15;
    int q = lane >> 4;
    const float* xrow = x + (size_t)(node0 + m) * IN_DIM;
    f32x4 acc0 = {0,0,0,0}, acc1 = {0,0,0,0}, acc2 = {0,0,0,0}, acc3 = {0,0,0,0};
#pragma unroll
    for (int kb = 0; kb < 4; ++kb) {
        int k0 = kb * 32 + q * 8;
        float4 a0 = *(const float4*)(xrow + k0);
        float4 a1 = *(const float4*)(xrow + k0 + 4);
        bf16x8 af;
        af[0]=f2bf(a0.x); af[1]=f2bf(a0.y); af[2]=f2bf(a0.z); af[3]=f2bf(a0.w);
        af[4]=f2bf(a1.x); af[5]=f2bf(a1.y); af[6]=f2bf(a1.z); af[7]=f2bf(a1.w);
        bf16x8 bf0 = *(const bf16x8*)(W1t + ( 0 + m) * IN_DIM + k0);
        bf16x8 bf1 = *(const bf16x8*)(W1t + (16 + m) * IN_DIM + k0);
        bf16x8 bf2 = *(const bf16x8*)(W1t + (32 + m) * IN_DIM + k0);
        bf16x8 bf3 = *(const bf16x8*)(W1t + (48 + m) * IN_DIM + k0);
        acc0 = __builtin_amdgcn_mfma_f32_16x16x32_bf16(af, bf0, acc0, 0, 0, 0);
        acc1 = __builtin_amdgcn_mfma_f32_16x16x32_bf16(af, bf1, acc1, 0, 0, 0);
        acc2 = __builtin_amdgcn_mfma_f32_16x16x32_bf16(af, bf2, acc2, 0, 0, 0);
        acc3 = __builtin_amdgcn_mfma_f32_16x16x32_bf16(af, bf3, acc3, 0, 0, 0);
    }
    f32x4 accs[4] = {acc0, acc1, acc2, acc3};
#pragma unroll
    for (int t = 0; t < 4; ++t) {
        float bias = b1[t * 16 + m];
#pragma unroll
        for (int r = 0; r < 4; ++r) {
            int node = node0 + q * 4 + r;            // C/D: col=lane&15, row=q*4+r
            out[(size_t)node * HID_DIM + t * 16 + m] = (unsigned short)f2bf(accs[t][r] + bias);
        }
    }
}

// ---------------- GEMM2 (MFMA): hbf_out[n,64] = bf16(relu(hbf[n,64]) @ W2 + b2) ----------------
__global__ __launch_bounds__(256) void gemm2_mfma(const unsigned short* __restrict__ h,
                                                  const short* __restrict__ W2t,
                                                  const float* __restrict__ b2,
                                                  unsigned short* __restrict__ out) {
    int wave = threadIdx.x >> 6;
    int lane = threadIdx.x & 63;
    int node0 = blockIdx.x * 64 + wave * 16;
    if (node0 >= N_NODES) return;
    int m = lane & 15;
    int q = lane >> 4;
    const unsigned short* hrow = h + (size_t)(node0 + m) * HID_DIM;
    f32x4 acc0 = {0,0,0,0}, acc1 = {0,0,0,0}, acc2 = {0,0,0,0}, acc3 = {0,0,0,0};
#pragma unroll
    for (int kb = 0; kb < 2; ++kb) {
        int k0 = kb * 32 + q * 8;
        bf16x8 af = *(const bf16x8*)(hrow + k0);
#pragma unroll
        for (int j = 0; j < 8; ++j)
            af[j] = ((unsigned short)af[j] & 0x8000u) ? 0 : af[j];   // bf16 ReLU
        bf16x8 bf0 = *(const bf16x8*)(W2t + ( 0 + m) * HID_DIM + k0);
        bf16x8 bf1 = *(const bf16x8*)(W2t + (16 + m) * HID_DIM + k0);
        bf16x8 bf2 = *(const bf16x8*)(W2t + (32 + m) * HID_DIM + k0);
        bf16x8 bf3 = *(const bf16x8*)(W2t + (48 + m) * HID_DIM + k0);
        acc0 = __builtin_amdgcn_mfma_f32_16x16x32_bf16(af, bf0, acc0, 0, 0, 0);
        acc1 = __builtin_amdgcn_mfma_f32_16x16x32_bf16(af, bf1, acc1, 0, 0, 0);
        acc2 = __builtin_amdgcn_mfma_f32_16x16x32_bf16(af, bf2, acc2, 0, 0, 0);
        acc3 = __builtin_amdgcn_mfma_f32_16x16x32_bf16(af, bf3, acc3, 0, 0, 0);
    }
    f32x4 accs[4] = {acc0, acc1, acc2, acc3};
#pragma unroll
    for (int t = 0; t < 4; ++t) {
        float bias = b2[t * 16 + m];
#pragma unroll
        for (int r = 0; r < 4; ++r) {
            int node = node0 + q * 4 + r;
            out[(size_t)node * HID_DIM + t * 16 + m] = (unsigned short)f2bf(accs[t][r] + bias);
        }
    }
}

// ---------------- Pass A v3: LDS-staged bucket sort, coalesced write-out ----------------
// 1024 threads, 6400 edges/block. Sort edges by bucket in LDS, then write each
// bucket's run contiguously so dirty lines get all bytes from adjacent lanes.
__global__ __launch_bounds__(PBLK) void part_a(const int* __restrict__ erow,
                                               const int* __restrict__ ecol,
                                               const float* __restrict__ eval,
                                               int* __restrict__ bcnt,
                                               int2* __restrict__ tmp) {
    __shared__ int2 pay[EPB];                 // 51.2 KB sorted payload
    __shared__ unsigned short sbuck[EPB];     // 12.8 KB bucket id per sorted slot
    __shared__ int hist[NBUCK], lbase[NBUCK], cur[NBUCK], dofs[NBUCK], scan[NBUCK]; // 15.6 KB
    int e0 = blockIdx.x * EPB;
    int tid = threadIdx.x;
    for (int i = tid; i < NBUCK; i += PBLK) { hist[i] = 0; cur[i] = 0; }
    __syncthreads();
    // phase 1: histogram
    for (int i = tid; i < EPB; i += PBLK)
        atomicAdd(&hist[erow[e0 + i] >> 7], 1);
    __syncthreads();
    // phase 2a: global reservation (absolute base in tmp)
    for (int i = tid; i < NBUCK; i += PBLK) {
        int n = hist[i];
        dofs[i] = i * BCAP + (n ? atomicAdd(&bcnt[i], n) : 0);   // abs gbase for now
        scan[i] = n;
    }
    __syncthreads();
    // phase 2b: exclusive scan of hist -> lbase
    for (int off = 1; off < NBUCK; off <<= 1) {
        int t = 0;
        if (tid < NBUCK && tid >= off) t = scan[tid - off];
        __syncthreads();
        if (tid < NBUCK) scan[tid] += t;
        __syncthreads();
    }
    if (tid < NBUCK) {
        lbase[tid] = scan[tid] - hist[tid];
        dofs[tid] -= lbase[tid];              // dest = dofs[b] + p
    }
    __syncthreads();
    // phase 3: scatter into LDS, sorted by bucket
    for (int i = tid; i < EPB; i += PBLK) {
        int e = e0 + i;
        int r = erow[e];
        int b = r >> 7;
        int p = lbase[b] + atomicAdd(&cur[b], 1);
        pay[p] = make_int2(((r & 127) << 17) | ecol[e], __float_as_int(eval[e]));
        sbuck[p] = (unsigned short)b;
    }
    __syncthreads();
    // phase 4: coalesced copy-out (consecutive p -> consecutive dest within bucket runs)
    for (int p = tid; p < EPB; p += PBLK) {
        int b = sbuck[p];
        int dest = dofs[b] + p;
        if (dest < (b + 1) * BCAP)            // capacity guard
            tmp[dest] = pay[p];
    }
}

// ---------------- Pass B: sort bucket by local row, pad each row to mult-of-8, col *= 64 ----------------
__global__ __launch_bounds__(256) void part_b(const int* __restrict__ bcnt,
                                              int2* __restrict__ tmp,
                                              int2* __restrict__ rowmeta) {
    __shared__ int2 ein[BCAP];       // 22.5 KB
    __shared__ int2 eout[BCAP];      // 22.5 KB
    __shared__ int hist[128], pad[128], basep[128], cur[128], scan[128];
    int b = blockIdx.x;
    int nb = bcnt[b]; if (nb > BCAP) nb = BCAP;
    for (int i = threadIdx.x; i < nb; i += 256) ein[i] = tmp[(size_t)b * BCAP + i];
    if (threadIdx.x < 128) { hist[threadIdx.x] = 0; cur[threadIdx.x] = 0; }
    __syncthreads();
    for (int i = threadIdx.x; i < nb; i += 256)
        atomicAdd(&hist[(ein[i].x >> 17) & 127], 1);
    __syncthreads();
    if (threadIdx.x < 128) {
        pad[threadIdx.x] = (hist[threadIdx.x] + 7) & ~7;   // pad to multiple of 8
        scan[threadIdx.x] = pad[threadIdx.x];
    }
    __syncthreads();
    for (int off = 1; off < 128; off <<= 1) {
        int t = 0;
        if (threadIdx.x < 128 && threadIdx.x >= off) t = scan[threadIdx.x - off];
        __syncthreads();
        if (threadIdx.x < 128) scan[threadIdx.x] += t;
        __syncthreads();
    }
    if (threadIdx.x < 128) basep[threadIdx.x] = scan[threadIdx.x] - pad[threadIdx.x];
    __syncthreads();
    int ntot = scan[127]; if (ntot > BCAP) ntot = BCAP;
    for (int i = threadIdx.x; i < nb; i += 256) {
        int lr = (ein[i].x >> 17) & 127;
        int p = basep[lr] + atomicAdd(&cur[lr], 1);
        if (p < BCAP) eout[p] = make_int2((ein[i].x & 0x1FFFF) << 6, ein[i].y);
    }
    __syncthreads();
    if (threadIdx.x < 128) {
        int pe = basep[threadIdx.x] + pad[threadIdx.x];
        for (int p = basep[threadIdx.x] + hist[threadIdx.x]; p < pe && p < BCAP; ++p)
            eout[p] = make_int2(0, 0);
    }
    __syncthreads();
    for (int i = threadIdx.x; i < ntot; i += 256) tmp[(size_t)b * BCAP + i] = eout[i];
    if (threadIdx.x < 128) {
        int r = b * 128 + threadIdx.x;
        if (r < N_NODES)
            rowmeta[r] = make_int2(b * BCAP + basep[threadIdx.x], pad[threadIdx.x]);
    }
}

// ---------------- SpMM v3: one wave per row; all gathers issued upfront (max MLP) ----------------
__global__ __launch_bounds__(256) void spmm_csr(const int2* __restrict__ rowmeta,
                                                const int2* __restrict__ ecv,
                                                const unsigned short* __restrict__ dense,
                                                unsigned short* __restrict__ out) {
    int r = blockIdx.x * 4 + (threadIdx.x >> 6);
    if (r >= N_NODES) return;
    int lane = threadIdx.x & 63;
    int g  = lane >> 3;
    int dq = lane & 7;
    int2 meta = rowmeta[r];
    int rs   = __builtin_amdgcn_readfirstlane(meta.x);
    int degp = __builtin_amdgcn_readfirstlane(meta.y);   // padded degree (multiple of 8)
    float a0=0,a1=0,a2=0,a3=0,a4=0,a5=0,a6=0,a7=0;
    if (degp > 0) {
        int2 em = ecv[rs + (lane < degp ? lane : degp - 1)];
        int iters = degp >> 3; if (iters > 8) iters = 8;
        uint4 d[8];
#pragma unroll
        for (int t = 0; t < 8; ++t) {
            if (t < iters) {
                int col = __shfl(em.x, t * 8 + g);
                d[t] = *(const uint4*)(dense + (size_t)col + (dq << 3));
            }
        }
#pragma unroll
        for (int t = 0; t < 8; ++t) {
            if (t < iters) {
                float v = __shfl(__int_as_float(em.y), t * 8 + g);
                a0 = fmaf(v, bflo(d[t].x), a0);  a1 = fmaf(v, bfhi(d[t].x), a1);
                a2 = fmaf(v, bflo(d[t].y), a2);  a3 = fmaf(v, bfhi(d[t].y), a3);
                a4 = fmaf(v, bflo(d[t].z), a4);  a5 = fmaf(v, bfhi(d[t].z), a5);
                a6 = fmaf(v, bflo(d[t].w), a6);  a7 = fmaf(v, bfhi(d[t].w), a7);
            }
        }
        for (int e = rs + 64; e < rs + degp; ++e) {
            int2 ee = ecv[e];
            if (g == 0) {
                float tv = __int_as_float(ee.y);
                uint4 td = *(const uint4*)(dense + (size_t)ee.x + (dq << 3));
                a0 = fmaf(tv, bflo(td.x), a0);  a1 = fmaf(tv, bfhi(td.x), a1);
                a2 = fmaf(tv, bflo(td.y), a2);  a3 = fmaf(tv, bfhi(td.y), a3);
                a4 = fmaf(tv, bflo(td.z), a4);  a5 = fmaf(tv, bfhi(td.z), a5);
                a6 = fmaf(tv, bflo(td.w), a6);  a7 = fmaf(tv, bfhi(td.w), a7);
            }
        }
    }
#pragma unroll
    for (int off = 8; off < 64; off <<= 1) {
        a0 += __shfl_xor(a0, off); a1 += __shfl_xor(a1, off);
        a2 += __shfl_xor(a2, off); a3 += __shfl_xor(a3, off);
        a4 += __shfl_xor(a4, off); a5 += __shfl_xor(a5, off);
        a6 += __shfl_xor(a6, off); a7 += __shfl_xor(a7, off);
    }
    if (lane < 8) {
        uint4 o;
        o.x = (unsigned short)f2bf(a0) | ((unsigned)(unsigned short)f2bf(a1) << 16);
        o.y = (unsigned short)f2bf(a2) | ((unsigned)(unsigned short)f2bf(a3) << 16);
        o.z = (unsigned short)f2bf(a4) | ((unsigned)(unsigned short)f2bf(a5) << 16);
        o.w = (unsigned short)f2bf(a6) | ((unsigned)(unsigned short)f2bf(a7) << 16);
        *(uint4*)(out + (size_t)r * HID_DIM + lane * 8) = o;
    }
}

// ---------------- Classifier (MFMA): out = log_softmax(h @ Wc + bc) ----------------
#define SLOGW 49
__global__ __launch_bounds__(256) void classify_mfma(const unsigned short* __restrict__ h,
                                                     const short* __restrict__ Wct,
                                                     const float* __restrict__ bc,
                                                     float* __restrict__ out) {
    __shared__ float slog[64 * SLOGW];
    __shared__ float smax[64], slse[64];
    int wave = threadIdx.x >> 6;
    int lane = threadIdx.x & 63;
    int node0 = blockIdx.x * 64;
    int wnode0 = node0 + wave * 16;
    int m = lane & 15;
    int q = lane >> 4;
    int arow = wnode0 + m; if (arow >= N_NODES) arow = N_NODES - 1;
    const unsigned short* hrow = h + (size_t)arow * HID_DIM;
    f32x4 acc0 = {0,0,0,0}, acc1 = {0,0,0,0}, acc2 = {0,0,0,0};
#pragma unroll
    for (int kb = 0; kb < 2; ++kb) {
        int k0 = kb * 32 + q * 8;
        bf16x8 af = *(const bf16x8*)(hrow + k0);
        bf16x8 bf0 = *(const bf16x8*)(Wct + ( 0 + m) * HID_DIM + k0);
        bf16x8 bf1 = *(const bf16x8*)(Wct + (16 + m) * HID_DIM + k0);
        bf16x8 bf2 = *(const bf16x8*)(Wct + (32 + m) * HID_DIM + k0);
        acc0 = __builtin_amdgcn_mfma_f32_16x16x32_bf16(af, bf0, acc0, 0, 0, 0);
        acc1 = __builtin_amdgcn_mfma_f32_16x16x32_bf16(af, bf1, acc1, 0, 0, 0);
        acc2 = __builtin_amdgcn_mfma_f32_16x16x32_bf16(af, bf2, acc2, 0, 0, 0);
    }
    f32x4 accs[3] = {acc0, acc1, acc2};
#pragma unroll
    for (int t = 0; t < 3; ++t) {
        int cls = t * 16 + m;
        float bias = (cls < N_CLASSES) ? bc[cls] : 0.f;
#pragma unroll
        for (int r = 0; r < 4; ++r) {
            int nl = wave * 16 + q * 4 + r;
            slog[nl * SLOGW + cls] = accs[t][r] + bias;
        }
    }
    __syncthreads();
    if (threadIdx.x < 64) {
        int nl = threadIdx.x;
        float mx = -1e30f;
        for (int c = 0; c < N_CLASSES; ++c) mx = fmaxf(mx, slog[nl * SLOGW + c]);
        float s = 0.f;
        for (int c = 0; c < N_CLASSES; ++c) s += expf(slog[nl * SLOGW + c] - mx);
        smax[nl] = mx;
        slse[nl] = logf(s);
    }
    __syncthreads();
    for (int i = threadIdx.x; i < 64 * N_CLASSES; i += 256) {
        long long gi = (long long)node0 * N_CLASSES + i;
        if (gi < (long long)N_NODES * N_CLASSES) {
            int nl = i / N_CLASSES, c = i - nl * N_CLASSES;
            out[gi] = slog[nl * SLOGW + c] - smax[nl] - slse[nl];
        }
    }
}

extern "C" void kernel_launch(void* const* d_in, const int* in_sizes, int n_in,
                              void* d_out, int out_size, void* d_ws, size_t ws_size,
                              hipStream_t stream) {
    const float* x    = (const float*)d_in[0];
    const int*   erow = (const int*)  d_in[1];
    const int*   ecol = (const int*)  d_in[2];
    const float* eval = (const float*)d_in[3];
    const float* W1   = (const float*)d_in[4];
    const float* b1   = (const float*)d_in[5];
    const float* W2   = (const float*)d_in[6];
    const float* b2   = (const float*)d_in[7];
    const float* Wc   = (const float*)d_in[8];
    const float* bc   = (const float*)d_in[9];
    float* out = (float*)d_out;

    // ---- workspace layout ----
    char* ws = (char*)d_ws;
    size_t off = 0;
    auto alloc = [&](size_t bytes) { char* p = ws + off; off += (bytes + 255) & ~(size_t)255; return p; };
    unsigned short* bufA = (unsigned short*)alloc((size_t)N_NODES * HID_DIM * sizeof(short)); // 12.8 MB
    unsigned short* bufB = (unsigned short*)alloc((size_t)N_NODES * HID_DIM * sizeof(short)); // 12.8 MB
    int2*  tmp     = (int2*) alloc((size_t)NBUCK * BCAP * sizeof(int2));       // 17.6 MB
    int2*  rowmeta = (int2*) alloc((size_t)N_NODES * sizeof(int2));            // 0.8 MB
    int*   bcnt    = (int*)  alloc(NBUCK * sizeof(int));
    short* W1t     = (short*)alloc((size_t)IN_DIM * HID_DIM * sizeof(short));
    short* W2t     = (short*)alloc((size_t)HID_DIM * HID_DIM * sizeof(short));
    short* Wct     = (short*)alloc((size_t)NCPAD * HID_DIM * sizeof(short));

    const int tile_grid = (N_NODES + 63) / 64;     // 1563
    const int spmm_grid = (N_NODES + 3) / 4;
    const int grid_a    = (N_EDGES + EPB - 1) / EPB;   // 250

    // ---- build bucketed padded CSR (reused by both spmm layers) + weight prep ----
    hipMemsetAsync(bcnt, 0, NBUCK * sizeof(int), stream);
    prep_weights<<<32, 256, 0, stream>>>(W1, W2, Wc, W1t, W2t, Wct);
    part_a<<<grid_a, PBLK, 0, stream>>>(erow, ecol, eval, bcnt, tmp);
    part_b<<<NBUCK, 256, 0, stream>>>(bcnt, tmp, rowmeta);

    // ---- layer 1 ----
    gemm1_mfma<<<tile_grid, 256, 0, stream>>>(x, W1t, b1, bufA);
    spmm_csr<<<spmm_grid, 256, 0, stream>>>(rowmeta, tmp, bufA, bufB);
    // ---- layer 2 (ReLU fused into gemm2 A-load) ----
    gemm2_mfma<<<tile_grid, 256, 0, stream>>>(bufB, W2t, b2, bufA);
    spmm_csr<<<spmm_grid, 256, 0, stream>>>(rowmeta, tmp, bufA, bufB);
    // ---- classifier + log-softmax ----
    classify_mfma<<<tile_grid, 256, 0, stream>>>(bufB, Wct, bc, out);
}